// Round 3
// baseline (247.874 us; speedup 1.0000x reference)
//
#include <hip/hip_runtime.h>
#include <math.h>

#define Bq 8
#define T 512
#define D 1024
#define R 4
#define V 2048
#define NCOL (V * R * R)        // 32768 columns of w_vocab
#define DSPLIT 8
#define DCHUNK (D / DSPLIT)     // 128 d-rows per k_core block
#define CBLK 512                // cols per k_core block (128 thr * float4)

// ---------------------------------------------------------------------------
// K1: xbar[b][d] = sum_t x[b][t][d]   (mean scale cancels in all normalizes)
// grid (8, 32) x 256 threads; each block sums 16 t's for all 1024 d via float4.
// Block (0,0) thread 0 also zeroes the output scalar (replaces a memset).
// ---------------------------------------------------------------------------
__global__ void k_xbar(const float* __restrict__ x, float* __restrict__ xbar,
                       float* __restrict__ out) {
    int b   = blockIdx.x;
    int tc  = blockIdx.y;          // 32 chunks of 16 timesteps
    int tid = threadIdx.x;         // 256 -> 1024 d via float4
    if (b == 0 && tc == 0 && tid == 0) out[0] = 0.f;
    const float4* xp = (const float4*)(x + ((size_t)b * T + (size_t)tc * 16) * D) + tid;
    float4 acc = make_float4(0.f, 0.f, 0.f, 0.f);
#pragma unroll
    for (int t = 0; t < 16; ++t) {
        float4 v = xp[t * (D / 4)];
        acc.x += v.x; acc.y += v.y; acc.z += v.z; acc.w += v.w;
    }
    float* dst = xbar + b * D + tid * 4;
    atomicAdd(dst + 0, acc.x);
    atomicAdd(dst + 1, acc.y);
    atomicAdd(dst + 2, acc.z);
    atomicAdd(dst + 3, acc.w);
}

// ---------------------------------------------------------------------------
// K2: part[ds][b][col] = sum_{d in chunk ds} xbar[b][d] * w_vocab[d][col]
// grid (64, 8) x 128 threads; each thread owns 4 cols (float4), 8 batches.
// Streams the full 128 MB of w_vocab exactly once; part is 8 MiB.
// unroll 8 -> 8 KB/wave in flight, 8 waves/CU.
// ---------------------------------------------------------------------------
__global__ void k_core(const float* __restrict__ wv, const float* __restrict__ xbar,
                       float* __restrict__ part) {
    __shared__ float xs[Bq * DCHUNK];  // 8 x 128 floats = 4 KB
    int tid  = threadIdx.x;            // 0..127
    int colb = blockIdx.x;             // 0..63
    int ds   = blockIdx.y;             // 0..7
    int d0   = ds * DCHUNK;

    {   // 128 threads load 8 floats each (slice is b-contiguous in 128-chunks)
        int l = tid * 8;
        int b = tid >> 4;              // l / DCHUNK
        int dd = l & (DCHUNK - 1);
        *(float4*)(xs + l)     = *(const float4*)(xbar + b * D + d0 + dd);
        *(float4*)(xs + l + 4) = *(const float4*)(xbar + b * D + d0 + dd + 4);
    }
    __syncthreads();

    int col = colb * CBLK + tid * 4;
    const float4* wp = (const float4*)(wv + (size_t)d0 * NCOL + col);
    float4 acc[Bq];
#pragma unroll
    for (int b = 0; b < Bq; ++b) acc[b] = make_float4(0.f, 0.f, 0.f, 0.f);

#pragma unroll 8
    for (int d = 0; d < DCHUNK; ++d) {
        float4 w = wp[(size_t)d * (NCOL / 4)];
#pragma unroll
        for (int b = 0; b < Bq; ++b) {
            float xv = xs[b * DCHUNK + d];
            acc[b].x += w.x * xv;
            acc[b].y += w.y * xv;
            acc[b].z += w.z * xv;
            acc[b].w += w.w * xv;
        }
    }

#pragma unroll
    for (int b = 0; b < Bq; ++b)
        *(float4*)(part + ((size_t)ds * Bq + b) * NCOL + col) = acc[b];
}

// ---------------------------------------------------------------------------
// K3 (fused gather + normalize + chain + finalize): one block per batch,
// 256 threads.
//  phase 0: alpha/beta partial dots (32 segs x {a,b} x 4 r)
//  phase 1: gather 512 matrices -> abs -> column-normalize -> LDS (32 KB)
//  phase 2: 64 chunk products of 8 matrices + 6-level in-order LDS tree
//  phase 3: v0 -> P v0 -> prob -> atomicAdd(-log(prob)/8)
// ---------------------------------------------------------------------------
__global__ void k_fuse(const float* __restrict__ part, const int* __restrict__ labels,
                       const float* __restrict__ xbar,
                       const float* __restrict__ wa, const float* __restrict__ wb,
                       float* __restrict__ out) {
    __shared__ float Mn_s[T * 16];    // 32 KB
    __shared__ float mats[64][17];    // +1 pad
    __shared__ float abp[256];
    int b   = blockIdx.x;
    int tid = threadIdx.x;            // 0..255

    // ---- phase 0: alpha/beta partial dots ----
    {
        int r   = tid & 3;
        int sel = (tid >> 2) & 1;
        int seg = tid >> 3;           // 0..31, 32 d each
        const float* w  = sel ? wb : wa;
        const float* xp = xbar + b * D;
        float s = 0.f;
#pragma unroll 8
        for (int d = seg * 32; d < seg * 32 + 32; ++d)
            s += xp[d] * w[d * R + r];
        abp[tid] = s;
    }

    // ---- phase 1: gather + column-normalize into LDS ----
    int tl = tid >> 2;                // 0..63
    int i  = tid & 3;                 // matrix row
#pragma unroll
    for (int tc = 0; tc < 8; ++tc) {
        int t = tc * 64 + tl;
        int y = labels[b * T + t];
        const float* pb = part + (size_t)b * NCOL + (size_t)i * (V * R) + (size_t)y * R;
        float4 g = make_float4(0.f, 0.f, 0.f, 0.f);
#pragma unroll
        for (int ds = 0; ds < DSPLIT; ++ds) {
            float4 v = *(const float4*)(pb + (size_t)ds * (Bq * NCOL));
            g.x += v.x; g.y += v.y; g.z += v.z; g.w += v.w;
        }
        g.x = fabsf(g.x); g.y = fabsf(g.y); g.z = fabsf(g.z); g.w = fabsf(g.w);

        // all-reduce over the 4-lane i-group (lanes differ in bits 0..1)
        float sx = g.x, sy = g.y, sz = g.z, sw = g.w;
        sx += __shfl_xor(sx, 1); sy += __shfl_xor(sy, 1);
        sz += __shfl_xor(sz, 1); sw += __shfl_xor(sw, 1);
        sx += __shfl_xor(sx, 2); sy += __shfl_xor(sy, 2);
        sz += __shfl_xor(sz, 2); sw += __shfl_xor(sw, 2);

        float4 o = make_float4(g.x / sx, g.y / sy, g.z / sz, g.w / sw);
        *(float4*)(Mn_s + t * 16 + i * 4) = o;
    }
    __syncthreads();

    // ---- phase 2: chunk product P = M_{c*8+7} ... M_{c*8} (tid < 64) ----
    int c = tid;
    float P[R][R];
    if (c < 64) {
        const float* mp = Mn_s + c * 8 * 16;
        {
            float4 m0 = *(const float4*)(mp + 0);
            float4 m1 = *(const float4*)(mp + 4);
            float4 m2 = *(const float4*)(mp + 8);
            float4 m3 = *(const float4*)(mp + 12);
            P[0][0]=m0.x; P[0][1]=m0.y; P[0][2]=m0.z; P[0][3]=m0.w;
            P[1][0]=m1.x; P[1][1]=m1.y; P[1][2]=m1.z; P[1][3]=m1.w;
            P[2][0]=m2.x; P[2][1]=m2.y; P[2][2]=m2.z; P[2][3]=m2.w;
            P[3][0]=m3.x; P[3][1]=m3.y; P[3][2]=m3.z; P[3][3]=m3.w;
        }
#pragma unroll
        for (int t = 1; t < 8; ++t) {
            float4 m0 = *(const float4*)(mp + t * 16 + 0);
            float4 m1 = *(const float4*)(mp + t * 16 + 4);
            float4 m2 = *(const float4*)(mp + t * 16 + 8);
            float4 m3 = *(const float4*)(mp + t * 16 + 12);
            float M[R][R] = {{m0.x, m0.y, m0.z, m0.w},
                             {m1.x, m1.y, m1.z, m1.w},
                             {m2.x, m2.y, m2.z, m2.w},
                             {m3.x, m3.y, m3.z, m3.w}};
            float N[R][R];
#pragma unroll
            for (int ii = 0; ii < R; ++ii)
#pragma unroll
                for (int j = 0; j < R; ++j)
                    N[ii][j] = M[ii][0] * P[0][j] + M[ii][1] * P[1][j] +
                               M[ii][2] * P[2][j] + M[ii][3] * P[3][j];
#pragma unroll
            for (int ii = 0; ii < R; ++ii)
#pragma unroll
                for (int j = 0; j < R; ++j) P[ii][j] = N[ii][j];
        }
#pragma unroll
        for (int ii = 0; ii < R; ++ii)
#pragma unroll
            for (int j = 0; j < R; ++j) mats[c][ii * 4 + j] = P[ii][j];
    }
    __syncthreads();

    // ---- in-order tree combine: C_c <- C_{c+step} * C_c ----
    for (int rnd = 0; rnd < 6; ++rnd) {
        int step = 1 << rnd;
        bool act = (c < 64) && ((c & (2 * step - 1)) == 0);
        float N2[R][R];
        if (act) {
            float A[R][R], Bm[R][R];
#pragma unroll
            for (int ii = 0; ii < R; ++ii)
#pragma unroll
                for (int j = 0; j < R; ++j) {
                    A[ii][j]  = mats[c + step][ii * 4 + j];
                    Bm[ii][j] = mats[c][ii * 4 + j];
                }
#pragma unroll
            for (int ii = 0; ii < R; ++ii)
#pragma unroll
                for (int j = 0; j < R; ++j)
                    N2[ii][j] = A[ii][0] * Bm[0][j] + A[ii][1] * Bm[1][j] +
                                A[ii][2] * Bm[2][j] + A[ii][3] * Bm[3][j];
        }
        __syncthreads();
        if (act) {
#pragma unroll
            for (int ii = 0; ii < R; ++ii)
#pragma unroll
                for (int j = 0; j < R; ++j) mats[c][ii * 4 + j] = N2[ii][j];
        }
        __syncthreads();
    }

    // ---- phase 3: finalize this batch ----
    if (tid == 0) {
        float a[R], be[R];
#pragma unroll
        for (int r = 0; r < R; ++r) {
            float sa = 0.f, sb = 0.f;
            for (int seg = 0; seg < 32; ++seg) {
                sa += abp[(seg << 3) | r];
                sb += abp[(seg << 3) | 4 | r];
            }
            a[r] = sa; be[r] = sb;
        }
        float sa = fabsf(a[0]) + fabsf(a[1]) + fabsf(a[2]) + fabsf(a[3]);
        float v0[R];
#pragma unroll
        for (int r = 0; r < R; ++r) v0[r] = fabsf(a[r]) / sa;
        float v[R];
#pragma unroll
        for (int ii = 0; ii < R; ++ii)
            v[ii] = mats[0][ii * 4 + 0] * v0[0] + mats[0][ii * 4 + 1] * v0[1] +
                    mats[0][ii * 4 + 2] * v0[2] + mats[0][ii * 4 + 3] * v0[3];
        float sb = fabsf(be[0]) + fabsf(be[1]) + fabsf(be[2]) + fabsf(be[3]);
        float prob = (fabsf(be[0]) * v[0] + fabsf(be[1]) * v[1] +
                      fabsf(be[2]) * v[2] + fabsf(be[3]) * v[3]) / sb;
        atomicAdd(out, -logf(prob) * 0.125f);
    }
}

extern "C" void kernel_launch(void* const* d_in, const int* in_sizes, int n_in,
                              void* d_out, int out_size, void* d_ws, size_t ws_size,
                              hipStream_t stream) {
    const float* x      = (const float*)d_in[0];   // [8,512,1024] fp32
    const int*   labels = (const int*)d_in[1];     // [8,512] int32
    const float* wa     = (const float*)d_in[2];   // [1024,4]
    const float* wb     = (const float*)d_in[3];   // [1024,4]
    const float* wv     = (const float*)d_in[4];   // [1024,32768]
    float* out = (float*)d_out;                    // scalar loss

    float* xbar = (float*)d_ws;                    // 8192 floats
    float* part = xbar + Bq * D;                   // 8*8*32768 floats = 8 MiB

    hipMemsetAsync(xbar, 0, Bq * D * sizeof(float), stream);
    k_xbar<<<dim3(Bq, 32), 256, 0, stream>>>(x, xbar, out);
    k_core<<<dim3(NCOL / CBLK, DSPLIT), 128, 0, stream>>>(wv, xbar, part);
    k_fuse<<<Bq, 256, 0, stream>>>(part, labels, xbar, wa, wb, out);
}

// Round 4
// 232.917 us; speedup vs baseline: 1.0642x; 1.0642x over previous
//
#include <hip/hip_runtime.h>
#include <math.h>

#define Bq 8
#define T 512
#define D 1024
#define R 4
#define V 2048
#define NCOL (V * R * R)        // 32768 columns of w_vocab
#define DSPLIT 16
#define DCHUNK (D / DSPLIT)     // 64 d-rows per k_core block
#define CBLK 1024               // cols per k_core block (256 thr * float4)
#define NTC 32                  // t-chunks in k_xbar (16 t each)

// ---------------------------------------------------------------------------
// K1: partial[b][tc][d] = sum of 16 t's of x[b][.][d].  No atomics, no memset.
// grid (8, 32) x 256 threads, float4 coalesced loads+stores.
// Block (0,0) thread 0 zeroes the output scalar (replaces a memset).
// ---------------------------------------------------------------------------
__global__ void k_xbar(const float* __restrict__ x, float* __restrict__ partial,
                       float* __restrict__ out) {
    int b   = blockIdx.x;
    int tc  = blockIdx.y;          // 32 chunks of 16 timesteps
    int tid = threadIdx.x;         // 256 -> 1024 d via float4
    if (b == 0 && tc == 0 && tid == 0) out[0] = 0.f;
    const float4* xp = (const float4*)(x + ((size_t)b * T + (size_t)tc * 16) * D) + tid;
    float4 acc = make_float4(0.f, 0.f, 0.f, 0.f);
#pragma unroll
    for (int t = 0; t < 16; ++t) {
        float4 v = xp[t * (D / 4)];
        acc.x += v.x; acc.y += v.y; acc.z += v.z; acc.w += v.w;
    }
    *(float4*)(partial + ((size_t)b * NTC + tc) * D + tid * 4) = acc;
}

// ---------------------------------------------------------------------------
// K2: part[ds][b][col] = sum_{d in chunk ds} xbar[b][d] * w_vocab[d][col]
// grid (32, 16) x 256 threads. Prologue reduces partial[b][tc][d-slice] ->
// xs in LDS (64 KiB of L2-resident reads, shared by 32 colb-blocks).
// colb==0 blocks also write xbar back to global for k_chain.
// Main loop streams the full 128 MB of w_vocab exactly once (8 waves/CU,
// unroll 8 -> 8 KB/wave in flight).
// ---------------------------------------------------------------------------
__global__ void k_core(const float* __restrict__ wv, const float* __restrict__ partial,
                       float* __restrict__ xbar, float* __restrict__ part) {
    __shared__ float xs[Bq * DCHUNK];  // 8 x 64 floats = 2 KB
    int tid  = threadIdx.x;            // 0..255
    int colb = blockIdx.x;             // 0..31
    int ds   = blockIdx.y;             // 0..15
    int d0   = ds * DCHUNK;

    // reduce partial -> xs (512 values, 2 per thread)
#pragma unroll
    for (int h = 0; h < 2; ++h) {
        int q  = tid + h * 256;        // 0..511
        int b  = q >> 6;
        int dd = q & 63;
        const float* pp = partial + (size_t)b * NTC * D + d0 + dd;
        float s = 0.f;
#pragma unroll
        for (int tc = 0; tc < NTC; ++tc) s += pp[(size_t)tc * D];
        xs[q] = s;
    }
    __syncthreads();

    if (colb == 0 && tid < 128) {      // write xbar slice back for k_chain
        int q4 = tid * 4;
        int b  = q4 >> 6;
        int dd = q4 & 63;
        *(float4*)(xbar + b * D + d0 + dd) = *(const float4*)(xs + q4);
    }

    int col = colb * CBLK + tid * 4;
    const float4* wp = (const float4*)(wv + (size_t)d0 * NCOL + col);
    float4 acc[Bq];
#pragma unroll
    for (int b = 0; b < Bq; ++b) acc[b] = make_float4(0.f, 0.f, 0.f, 0.f);

#pragma unroll 8
    for (int d = 0; d < DCHUNK; ++d) {
        float4 w = wp[(size_t)d * (NCOL / 4)];
#pragma unroll
        for (int b = 0; b < Bq; ++b) {
            float xv = xs[b * DCHUNK + d];
            acc[b].x += w.x * xv;
            acc[b].y += w.y * xv;
            acc[b].z += w.z * xv;
            acc[b].w += w.w * xv;
        }
    }

#pragma unroll
    for (int b = 0; b < Bq; ++b)
        *(float4*)(part + ((size_t)ds * Bq + b) * NCOL + col) = acc[b];
}

// ---------------------------------------------------------------------------
// K3: gather + column-normalize. grid (8 b, 8 tchunk) x 256 threads.
// thread = (t_local, i): 16 independent float4 loads in flight,
// column sums over i via shfl_xor within the 4-lane group.
// ---------------------------------------------------------------------------
__global__ void k_gather(const float* __restrict__ part, const int* __restrict__ labels,
                         float* __restrict__ Mn) {
    int b   = blockIdx.x;
    int tc  = blockIdx.y;
    int tid = threadIdx.x;
    int tl  = tid >> 2;               // 0..63
    int i   = tid & 3;                // matrix row
    int t   = tc * 64 + tl;
    int y   = labels[b * T + t];

    const float* pb = part + (size_t)b * NCOL + (size_t)i * (V * R) + (size_t)y * R;
    float4 g = make_float4(0.f, 0.f, 0.f, 0.f);
#pragma unroll
    for (int ds = 0; ds < DSPLIT; ++ds) {
        float4 v = *(const float4*)(pb + (size_t)ds * (Bq * NCOL));
        g.x += v.x; g.y += v.y; g.z += v.z; g.w += v.w;
    }
    g.x = fabsf(g.x); g.y = fabsf(g.y); g.z = fabsf(g.z); g.w = fabsf(g.w);

    float sx = g.x, sy = g.y, sz = g.z, sw = g.w;
    sx += __shfl_xor(sx, 1); sy += __shfl_xor(sy, 1);
    sz += __shfl_xor(sz, 1); sw += __shfl_xor(sw, 1);
    sx += __shfl_xor(sx, 2); sy += __shfl_xor(sy, 2);
    sz += __shfl_xor(sz, 2); sw += __shfl_xor(sw, 2);

    float4 o = make_float4(g.x / sx, g.y / sy, g.z / sz, g.w / sw);
    *(float4*)(Mn + ((size_t)(b * T + t)) * 16 + i * 4) = o;
}

// ---------------------------------------------------------------------------
// K4: one block per batch, 64 threads (1 wave). Phase 0: alpha/beta dots.
// Phase 1: per-thread 8-matrix chunk products + 6-level in-order LDS tree.
// Phase 2: v0 -> P v0 -> prob -> atomicAdd(-log(prob)/8) into zeroed out.
// ---------------------------------------------------------------------------
__global__ void k_chain(const float* __restrict__ Mn, const float* __restrict__ xbar,
                        const float* __restrict__ wa, const float* __restrict__ wb,
                        float* __restrict__ out) {
    __shared__ float mats[64][17];    // +1 pad
    __shared__ float abp[64];
    int b   = blockIdx.x;
    int tid = threadIdx.x;            // 0..63

    // ---- phase 0: alpha/beta partial dots (8 segs x {a,b} x 4 r) ----
    {
        int r   = tid & 3;
        int sel = (tid >> 2) & 1;
        int seg = tid >> 3;           // 0..7, 128 d each
        const float* w  = sel ? wb : wa;
        const float* xp = xbar + b * D;
        float s = 0.f;
#pragma unroll 8
        for (int d = seg * 128; d < seg * 128 + 128; ++d)
            s += xp[d] * w[d * R + r];
        abp[tid] = s;
    }

    // ---- phase 1: chunk product P = M_{c*8+7} ... M_{c*8} ----
    int c = tid;
    const float* mp = Mn + ((size_t)b * T + (size_t)c * 8) * 16;
    float P[R][R];
    {
        float4 m0 = *(const float4*)(mp + 0);
        float4 m1 = *(const float4*)(mp + 4);
        float4 m2 = *(const float4*)(mp + 8);
        float4 m3 = *(const float4*)(mp + 12);
        P[0][0]=m0.x; P[0][1]=m0.y; P[0][2]=m0.z; P[0][3]=m0.w;
        P[1][0]=m1.x; P[1][1]=m1.y; P[1][2]=m1.z; P[1][3]=m1.w;
        P[2][0]=m2.x; P[2][1]=m2.y; P[2][2]=m2.z; P[2][3]=m2.w;
        P[3][0]=m3.x; P[3][1]=m3.y; P[3][2]=m3.z; P[3][3]=m3.w;
    }
#pragma unroll
    for (int t = 1; t < 8; ++t) {
        float4 m0 = *(const float4*)(mp + t * 16 + 0);
        float4 m1 = *(const float4*)(mp + t * 16 + 4);
        float4 m2 = *(const float4*)(mp + t * 16 + 8);
        float4 m3 = *(const float4*)(mp + t * 16 + 12);
        float M[R][R] = {{m0.x, m0.y, m0.z, m0.w},
                         {m1.x, m1.y, m1.z, m1.w},
                         {m2.x, m2.y, m2.z, m2.w},
                         {m3.x, m3.y, m3.z, m3.w}};
        float N[R][R];
#pragma unroll
        for (int i = 0; i < R; ++i)
#pragma unroll
            for (int j = 0; j < R; ++j)
                N[i][j] = M[i][0] * P[0][j] + M[i][1] * P[1][j] +
                          M[i][2] * P[2][j] + M[i][3] * P[3][j];
#pragma unroll
        for (int i = 0; i < R; ++i)
#pragma unroll
            for (int j = 0; j < R; ++j) P[i][j] = N[i][j];
    }
#pragma unroll
    for (int i = 0; i < R; ++i)
#pragma unroll
        for (int j = 0; j < R; ++j) mats[c][i * 4 + j] = P[i][j];
    __syncthreads();

    // ---- in-order tree combine: C_c <- C_{c+step} * C_c ----
    for (int rnd = 0; rnd < 6; ++rnd) {
        int step = 1 << rnd;
        bool act = ((c & (2 * step - 1)) == 0);
        float N2[R][R];
        if (act) {
            float A[R][R], Bm[R][R];
#pragma unroll
            for (int i = 0; i < R; ++i)
#pragma unroll
                for (int j = 0; j < R; ++j) {
                    A[i][j]  = mats[c + step][i * 4 + j];
                    Bm[i][j] = mats[c][i * 4 + j];
                }
#pragma unroll
            for (int i = 0; i < R; ++i)
#pragma unroll
                for (int j = 0; j < R; ++j)
                    N2[i][j] = A[i][0] * Bm[0][j] + A[i][1] * Bm[1][j] +
                               A[i][2] * Bm[2][j] + A[i][3] * Bm[3][j];
        }
        __syncthreads();
        if (act) {
#pragma unroll
            for (int i = 0; i < R; ++i)
#pragma unroll
                for (int j = 0; j < R; ++j) mats[c][i * 4 + j] = N2[i][j];
        }
        __syncthreads();
    }

    // ---- phase 2: finalize this batch ----
    if (tid == 0) {
        float a[R], be[R];
#pragma unroll
        for (int r = 0; r < R; ++r) {
            float sa = 0.f, sb = 0.f;
#pragma unroll
            for (int seg = 0; seg < 8; ++seg) {
                sa += abp[(seg << 3) | r];
                sb += abp[(seg << 3) | 4 | r];
            }
            a[r] = sa; be[r] = sb;
        }
        float sa = fabsf(a[0]) + fabsf(a[1]) + fabsf(a[2]) + fabsf(a[3]);
        float v0[R];
#pragma unroll
        for (int r = 0; r < R; ++r) v0[r] = fabsf(a[r]) / sa;
        float v[R];
#pragma unroll
        for (int i = 0; i < R; ++i)
            v[i] = mats[0][i * 4 + 0] * v0[0] + mats[0][i * 4 + 1] * v0[1] +
                   mats[0][i * 4 + 2] * v0[2] + mats[0][i * 4 + 3] * v0[3];
        float sb = fabsf(be[0]) + fabsf(be[1]) + fabsf(be[2]) + fabsf(be[3]);
        float prob = (fabsf(be[0]) * v[0] + fabsf(be[1]) * v[1] +
                      fabsf(be[2]) * v[2] + fabsf(be[3]) * v[3]) / sb;
        atomicAdd(out, -logf(prob) * 0.125f);
    }
}

extern "C" void kernel_launch(void* const* d_in, const int* in_sizes, int n_in,
                              void* d_out, int out_size, void* d_ws, size_t ws_size,
                              hipStream_t stream) {
    const float* x      = (const float*)d_in[0];   // [8,512,1024] fp32
    const int*   labels = (const int*)d_in[1];     // [8,512] int32
    const float* wa     = (const float*)d_in[2];   // [1024,4]
    const float* wb     = (const float*)d_in[3];   // [1024,4]
    const float* wv     = (const float*)d_in[4];   // [1024,32768]
    float* out = (float*)d_out;                    // scalar loss

    float* xbar    = (float*)d_ws;                           // 8192 floats
    float* partial = xbar + Bq * D;                          // 8*32*1024 = 1 MiB
    float* part    = partial + (size_t)Bq * NTC * D;         // 16*8*32768 = 16 MiB
    float* Mn      = part + (size_t)DSPLIT * Bq * NCOL;      // 65536 floats

    k_xbar<<<dim3(Bq, NTC), 256, 0, stream>>>(x, partial, out);
    k_core<<<dim3(NCOL / CBLK, DSPLIT), 256, 0, stream>>>(wv, partial, xbar, part);
    k_gather<<<dim3(Bq, T / 64), 256, 0, stream>>>(part, labels, Mn);
    k_chain<<<Bq, 64, 0, stream>>>(Mn, xbar, wa, wb, out);
}